// Round 1
// baseline (562.229 us; speedup 1.0000x reference)
//
#include <hip/hip_runtime.h>
#include <hip/hip_bf16.h>
#include <stdint.h>

#define NTOK 8192
#define DDIM 1024
#define HDIM 512

typedef __attribute__((ext_vector_type(8))) __bf16 bf16x8;
typedef __attribute__((ext_vector_type(4))) float f32x4;
typedef __attribute__((ext_vector_type(4))) uint32_t u32x4;

__device__ __forceinline__ void gload16(const void* g, void* lds) {
  __builtin_amdgcn_global_load_lds(
      (const __attribute__((address_space(1))) void*)g,
      (__attribute__((address_space(3))) void*)lds,
      16, 0, 0);
}

// ---------------- conversion kernels ----------------

__global__ void convert_x_kernel(const float* __restrict__ in, __hip_bfloat16* __restrict__ out) {
  size_t i = ((size_t)blockIdx.x * 256 + threadIdx.x) * 8;
  float4 a = *(const float4*)(in + i);
  float4 b = *(const float4*)(in + i + 4);
  union { __hip_bfloat16 h[8]; u32x4 u; } cv;
  cv.h[0] = __float2bfloat16(a.x); cv.h[1] = __float2bfloat16(a.y);
  cv.h[2] = __float2bfloat16(a.z); cv.h[3] = __float2bfloat16(a.w);
  cv.h[4] = __float2bfloat16(b.x); cv.h[5] = __float2bfloat16(b.y);
  cv.h[6] = __float2bfloat16(b.z); cv.h[7] = __float2bfloat16(b.w);
  *(u32x4*)((char*)out + i * 2) = cv.u;
}

// in [B][K][Nn] fp32 -> out [B][Nn][K] bf16 (transpose + convert)
__global__ void convert_w_kernel(const float* __restrict__ in, __hip_bfloat16* __restrict__ out,
                                 int K, int Nn) {
  __shared__ float tile[32][33];
  const float* src = in + (size_t)blockIdx.z * K * Nn;
  __hip_bfloat16* dst = out + (size_t)blockIdx.z * K * Nn;
  int n0 = blockIdx.x * 32, k0 = blockIdx.y * 32;
  int c = threadIdx.x & 31, r = threadIdx.x >> 5;
  #pragma unroll
  for (int i = 0; i < 4; i++)
    tile[r + i * 8][c] = src[(size_t)(k0 + r + i * 8) * Nn + n0 + c];
  __syncthreads();
  #pragma unroll
  for (int i = 0; i < 4; i++)
    dst[(size_t)(n0 + r + i * 8) * K + k0 + c] = __float2bfloat16(tile[c][r + i * 8]);
}

// ---------------- routing ----------------

__global__ void routing_kernel(const float* __restrict__ X, const float* __restrict__ rW,
                               const float* __restrict__ ebias, int* __restrict__ top_e,
                               float* __restrict__ top_w, int* __restrict__ counts) {
  int wid = threadIdx.x >> 6, lane = threadIdx.x & 63;
  int tok = blockIdx.x * 4 + wid;
  const float4* xr = (const float4*)(X + (size_t)tok * DDIM);
  float acc[8];
  #pragma unroll
  for (int e = 0; e < 8; e++) acc[e] = 0.f;
  #pragma unroll
  for (int c = 0; c < 4; c++) {
    int j = lane + c * 64;
    float4 x = xr[j];
    #pragma unroll
    for (int e = 0; e < 8; e++) {
      float4 w = ((const float4*)(rW + (size_t)e * DDIM))[j];
      acc[e] += x.x * w.x + x.y * w.y + x.z * w.z + x.w * w.w;
    }
  }
  #pragma unroll
  for (int m = 1; m < 64; m <<= 1)
    #pragma unroll
    for (int e = 0; e < 8; e++) acc[e] += __shfl_xor(acc[e], m, 64);
  if (lane == 0) {
    float act[8];
    #pragma unroll
    for (int e = 0; e < 8; e++) {
      float x = acc[e] + ebias[e];
      float sp = (x > 15.f) ? x : log1pf(expf(x));
      act[e] = sqrtf(sp);
    }
    int e1 = 0; float v1 = act[0];
    #pragma unroll
    for (int e = 1; e < 8; e++) if (act[e] > v1) { v1 = act[e]; e1 = e; }
    int e2 = -1; float v2 = -1.f;
    #pragma unroll
    for (int e = 0; e < 8; e++) if (e != e1 && act[e] > v2) { v2 = act[e]; e2 = e; }
    top_e[tok * 2] = e1; top_e[tok * 2 + 1] = e2;
    top_w[tok * 2] = v1; top_w[tok * 2 + 1] = v2;
    atomicAdd(&counts[e1], 1);
    atomicAdd(&counts[e2], 1);
  }
}

__global__ void scan_kernel(const int* __restrict__ counts, int* __restrict__ offs) {
  if (threadIdx.x == 0) {
    int s = 0;
    for (int e = 0; e < 8; e++) { offs[e] = s; s += counts[e]; }
    offs[8] = s;
  }
}

__global__ void scatter_kernel(const int* __restrict__ top_e, const float* __restrict__ top_w,
                               const int* __restrict__ offs, int* __restrict__ slot_ctr,
                               int* __restrict__ list, float* __restrict__ wlist) {
  int t = blockIdx.x * 256 + threadIdx.x;
  if (t >= NTOK) return;
  #pragma unroll
  for (int k = 0; k < 2; k++) {
    int e = top_e[t * 2 + k];
    float w = top_w[t * 2 + k];
    int p = atomicAdd(&slot_ctr[e], 1);
    int pos = offs[e] + p;
    list[pos] = t;
    wlist[pos] = w;
  }
}

// ---------------- GEMM (m97-style 128x128 tile, BK=32) ----------------
// MODE 1: H = silu(X @ W1 + b1)   [shared blocks + routed gather blocks], K=1024, N=512
// MODE 2: out = Hs @ sW2 + sb2    [shared only, plain store],            K=512,  N=1024
// MODE 3: out += w * (Hr @ rW2 + rb2) [routed only, atomicAdd scatter],  K=512,  N=1024

template<int MODE>
__global__ __launch_bounds__(256, 2)
void gemm_kernel(const __hip_bfloat16* __restrict__ Abase,
                 const __hip_bfloat16* __restrict__ Ws,
                 const __hip_bfloat16* __restrict__ Wr,
                 const float* __restrict__ bs,
                 const float* __restrict__ br,
                 __hip_bfloat16* __restrict__ Hout,
                 float* __restrict__ Oout,
                 const int* __restrict__ counts,
                 const int* __restrict__ offs,
                 const int* __restrict__ list,
                 const float* __restrict__ wlist) {
  constexpr int K  = (MODE == 1) ? 1024 : 512;
  constexpr int NN = (MODE == 1) ? 512 : 1024;
  constexpr int LDB = K * 2;  // row bytes for both A and B (n-major weights)

  __shared__ __hip_bfloat16 Abuf[128 * 32];
  __shared__ __hip_bfloat16 Bbuf[128 * 32];
  __shared__ int tokens[128];

  int bid = blockIdx.x;
  int e = 0, mt, nt;
  bool rb = false;
  if (MODE == 1) {
    if (bid < 256) { mt = bid >> 2; nt = bid & 3; }
    else { rb = true; int q = bid - 256; e = q >> 8; q &= 255; mt = q >> 2; nt = q & 3; }
  } else if (MODE == 2) { mt = bid >> 3; nt = bid & 7; }
  else { rb = true; e = bid >> 9; int q = bid & 511; mt = q >> 3; nt = q & 7; }
  int m0 = mt * 128;
  int cnt = 128;
  if (rb) {
    int ce = counts[e];
    if (m0 >= ce) return;
    cnt = (ce - m0 < 128) ? (ce - m0) : 128;
  }

  const __hip_bfloat16* W = rb ? (Wr + (size_t)e * NN * K) : Ws;
  const float* bias = rb ? (br + e * NN) : bs;

  int tid = threadIdx.x, wid = tid >> 6, lane = tid & 63;
  if (MODE == 1) {
    if (tid < 128)
      tokens[tid] = rb ? ((tid < cnt) ? list[offs[e] + m0 + tid] : 0) : (m0 + tid);
    __syncthreads();
  }
  int arow0 = (MODE == 2) ? m0 : ((MODE == 3) ? (NTOK + offs[e] + m0) : 0);

  // staging source pointers (per-lane global addr; LDS written linearly by gload_lds)
  const char* aSrc[2];
  const char* bSrc[2];
  int ldsOff[2];
  #pragma unroll
  for (int c = 0; c < 2; c++) {
    int s = c * 4096 + wid * 1024 + lane * 16;
    int row = s >> 6;
    int chunk = (s >> 4) & 3;
    int sc = chunk ^ (row & 3);  // XOR-swizzle: pre-swizzled global source
    long ar = (MODE == 1) ? (long)tokens[row] : (long)(arow0 + row);
    aSrc[c] = (const char*)Abase + (size_t)ar * LDB + sc * 16;
    bSrc[c] = (const char*)W + (size_t)(nt * 128 + row) * LDB + sc * 16;
    ldsOff[c] = c * 4096 + wid * 1024;
  }

  int wm = wid >> 1, wn = wid & 1;
  int aoff[4], boff[4];
  #pragma unroll
  for (int m = 0; m < 4; m++) {
    int row = wm * 64 + m * 16 + (lane & 15);
    aoff[m] = row * 64 + (((lane >> 4) ^ (row & 3)) << 4);
  }
  #pragma unroll
  for (int n = 0; n < 4; n++) {
    int row = wn * 64 + n * 16 + (lane & 15);
    boff[n] = row * 64 + (((lane >> 4) ^ (row & 3)) << 4);
  }

  f32x4 zero = {0.f, 0.f, 0.f, 0.f};
  f32x4 acc[4][4];
  #pragma unroll
  for (int m = 0; m < 4; m++)
    #pragma unroll
    for (int n = 0; n < 4; n++) acc[m][n] = zero;

  char* ldsA = (char*)&Abuf[0];
  char* ldsB = (char*)&Bbuf[0];

  for (int kt = 0; kt < K / 32; ++kt) {
    __syncthreads();
    #pragma unroll
    for (int c = 0; c < 2; c++) gload16(aSrc[c] + (size_t)kt * 64, ldsA + ldsOff[c]);
    #pragma unroll
    for (int c = 0; c < 2; c++) gload16(bSrc[c] + (size_t)kt * 64, ldsB + ldsOff[c]);
    __syncthreads();
    bf16x8 a[4], b[4];
    #pragma unroll
    for (int m = 0; m < 4; m++) a[m] = *(const bf16x8*)(ldsA + aoff[m]);
    #pragma unroll
    for (int n = 0; n < 4; n++) b[n] = *(const bf16x8*)(ldsB + boff[n]);
    #pragma unroll
    for (int m = 0; m < 4; m++)
      #pragma unroll
      for (int n = 0; n < 4; n++)
        acc[m][n] = __builtin_amdgcn_mfma_f32_16x16x32_bf16(a[m], b[n], acc[m][n], 0, 0, 0);
  }

  int colBase = nt * 128 + wn * 64;
  if (MODE == 1) {
    size_t hrow0 = rb ? (size_t)(NTOK + offs[e] + m0) : (size_t)m0;
    #pragma unroll
    for (int m = 0; m < 4; m++) {
      #pragma unroll
      for (int r = 0; r < 4; r++) {
        int rl = wm * 64 + m * 16 + ((lane >> 4) << 2) + r;
        if (rl < cnt) {
          #pragma unroll
          for (int n = 0; n < 4; n++) {
            int col = colBase + n * 16 + (lane & 15);
            float v = acc[m][n][r] + bias[col];
            v = v / (1.f + __expf(-v));  // silu
            Hout[(hrow0 + rl) * HDIM + col] = __float2bfloat16(v);
          }
        }
      }
    }
  } else if (MODE == 2) {
    #pragma unroll
    for (int m = 0; m < 4; m++) {
      #pragma unroll
      for (int r = 0; r < 4; r++) {
        int rl = wm * 64 + m * 16 + ((lane >> 4) << 2) + r;
        size_t orow = (size_t)(m0 + rl);
        #pragma unroll
        for (int n = 0; n < 4; n++) {
          int col = colBase + n * 16 + (lane & 15);
          Oout[orow * DDIM + col] = acc[m][n][r] + bias[col];
        }
      }
    }
  } else {
    #pragma unroll
    for (int m = 0; m < 4; m++) {
      #pragma unroll
      for (int r = 0; r < 4; r++) {
        int rl = wm * 64 + m * 16 + ((lane >> 4) << 2) + r;
        if (rl < cnt) {
          int pos = offs[e] + m0 + rl;
          int tok = list[pos];
          float w = wlist[pos];
          #pragma unroll
          for (int n = 0; n < 4; n++) {
            int col = colBase + n * 16 + (lane & 15);
            atomicAdd(&Oout[(size_t)tok * DDIM + col], w * (acc[m][n][r] + bias[col]));
          }
        }
      }
    }
  }
}

// ---------------- launch ----------------

extern "C" void kernel_launch(void* const* d_in, const int* in_sizes, int n_in,
                              void* d_out, int out_size, void* d_ws, size_t ws_size,
                              hipStream_t stream) {
  const float* X   = (const float*)d_in[0];
  const float* rWt = (const float*)d_in[1];
  const float* eb  = (const float*)d_in[2];
  const float* sW1 = (const float*)d_in[3];
  const float* sb1 = (const float*)d_in[4];
  const float* sW2 = (const float*)d_in[5];
  const float* sb2 = (const float*)d_in[6];
  const float* rW1 = (const float*)d_in[7];
  const float* rb1 = (const float*)d_in[8];
  const float* rW2 = (const float*)d_in[9];
  const float* rb2 = (const float*)d_in[10];
  float* out = (float*)d_out;

  char* ws = (char*)d_ws;
  size_t off = 0;
  auto alloc = [&](size_t bytes) {
    char* p = ws + off;
    off += (bytes + 255) & ~(size_t)255;
    return p;
  };
  __hip_bfloat16* Xb   = (__hip_bfloat16*)alloc((size_t)NTOK * DDIM * 2);
  __hip_bfloat16* sW1t = (__hip_bfloat16*)alloc((size_t)HDIM * DDIM * 2);
  __hip_bfloat16* sW2t = (__hip_bfloat16*)alloc((size_t)DDIM * HDIM * 2);
  __hip_bfloat16* rW1t = (__hip_bfloat16*)alloc((size_t)8 * HDIM * DDIM * 2);
  __hip_bfloat16* rW2t = (__hip_bfloat16*)alloc((size_t)8 * DDIM * HDIM * 2);
  // Hbuf rows: [0,8192) shared H, [8192, 8192+16384) routed H (by assignment slot)
  __hip_bfloat16* Hbuf = (__hip_bfloat16*)alloc((size_t)(NTOK + 2 * NTOK) * HDIM * 2);
  alloc(131072);  // pad: MODE3 partial-tile A reads may run past Hbuf end
  int* counts   = (int*)alloc(64);  // counts[8] + slot_ctr[8]
  int* slot_ctr = counts + 8;
  int* offsA    = (int*)alloc(64);
  int* top_e    = (int*)alloc((size_t)NTOK * 2 * 4);
  float* top_w  = (float*)alloc((size_t)NTOK * 2 * 4);
  int* list     = (int*)alloc((size_t)NTOK * 2 * 4);
  float* wlist  = (float*)alloc((size_t)NTOK * 2 * 4);

  hipMemsetAsync(counts, 0, 64, stream);
  convert_x_kernel<<<4096, 256, 0, stream>>>(X, Xb);
  convert_w_kernel<<<dim3(16, 32, 1), 256, 0, stream>>>(sW1, sW1t, 1024, 512);
  convert_w_kernel<<<dim3(32, 16, 1), 256, 0, stream>>>(sW2, sW2t, 512, 1024);
  convert_w_kernel<<<dim3(16, 32, 8), 256, 0, stream>>>(rW1, rW1t, 1024, 512);
  convert_w_kernel<<<dim3(32, 16, 8), 256, 0, stream>>>(rW2, rW2t, 512, 1024);
  routing_kernel<<<2048, 256, 0, stream>>>(X, rWt, eb, top_e, top_w, counts);
  scan_kernel<<<1, 64, 0, stream>>>(counts, offsA);
  scatter_kernel<<<32, 256, 0, stream>>>(top_e, top_w, offsA, slot_ctr, list, wlist);
  gemm_kernel<1><<<256 + 8 * 64 * 4, 256, 0, stream>>>(Xb, sW1t, rW1t, sb1, rb1, Hbuf, out,
                                                       counts, offsA, list, wlist);
  gemm_kernel<2><<<64 * 8, 256, 0, stream>>>(Hbuf, sW2t, rW2t, sb2, rb2, nullptr, out,
                                             counts, offsA, list, wlist);
  gemm_kernel<3><<<8 * 64 * 8, 256, 0, stream>>>(Hbuf, sW2t, rW2t, sb2, rb2, nullptr, out,
                                                 counts, offsA, list, wlist);
}

// Round 2
// 331.615 us; speedup vs baseline: 1.6954x; 1.6954x over previous
//
#include <hip/hip_runtime.h>
#include <hip/hip_bf16.h>
#include <stdint.h>

#define NTOK 8192
#define DDIM 1024
#define HDIM 512

typedef __attribute__((ext_vector_type(8))) __bf16 bf16x8;
typedef __attribute__((ext_vector_type(4))) float f32x4;
typedef __attribute__((ext_vector_type(4))) uint32_t u32x4;
typedef __attribute__((ext_vector_type(2))) uint32_t u32x2;

__device__ __forceinline__ void gload16(const void* g, void* lds) {
  __builtin_amdgcn_global_load_lds(
      (const __attribute__((address_space(1))) void*)g,
      (__attribute__((address_space(3))) void*)lds,
      16, 0, 0);
}

// ---------------- fused X convert + routing (NO global atomics) ----------------
// One wave per token: read 1024 fp32 (coalesced float4/lane), write bf16 copy,
// accumulate 8 expert logits, wave-reduce, lane0 does softplus/sqrt/top2.

__global__ __launch_bounds__(256)
void convert_route_kernel(const float* __restrict__ X, const float* __restrict__ rW,
                          const float* __restrict__ ebias,
                          __hip_bfloat16* __restrict__ Xb,
                          int* __restrict__ top_e, float* __restrict__ top_w) {
  int wid = threadIdx.x >> 6, lane = threadIdx.x & 63;
  int tok = blockIdx.x * 4 + wid;
  const float4* xr = (const float4*)(X + (size_t)tok * DDIM);
  u32x2* xb = (u32x2*)(Xb + (size_t)tok * DDIM);
  float acc[8];
  #pragma unroll
  for (int e = 0; e < 8; e++) acc[e] = 0.f;
  #pragma unroll
  for (int c = 0; c < 4; c++) {
    int j = c * 64 + lane;
    float4 x = xr[j];
    union { __hip_bfloat16 h[4]; u32x2 u; } cv;
    cv.h[0] = __float2bfloat16(x.x); cv.h[1] = __float2bfloat16(x.y);
    cv.h[2] = __float2bfloat16(x.z); cv.h[3] = __float2bfloat16(x.w);
    xb[j] = cv.u;
    #pragma unroll
    for (int e = 0; e < 8; e++) {
      float4 w = ((const float4*)(rW + (size_t)e * DDIM))[j];
      acc[e] += x.x * w.x + x.y * w.y + x.z * w.z + x.w * w.w;
    }
  }
  #pragma unroll
  for (int m = 1; m < 64; m <<= 1)
    #pragma unroll
    for (int e = 0; e < 8; e++) acc[e] += __shfl_xor(acc[e], m, 64);
  if (lane == 0) {
    float act[8];
    #pragma unroll
    for (int e = 0; e < 8; e++) {
      float x = acc[e] + ebias[e];
      float sp = (x > 15.f) ? x : log1pf(expf(x));
      act[e] = sqrtf(sp);
    }
    int e1 = 0; float v1 = act[0];
    #pragma unroll
    for (int e = 1; e < 8; e++) if (act[e] > v1) { v1 = act[e]; e1 = e; }
    int e2 = -1; float v2 = -1.f;
    #pragma unroll
    for (int e = 0; e < 8; e++) if (e != e1 && act[e] > v2) { v2 = act[e]; e2 = e; }
    top_e[tok * 2] = e1; top_e[tok * 2 + 1] = e2;
    top_w[tok * 2] = v1; top_w[tok * 2 + 1] = v2;
  }
}

// in [B][K][Nn] fp32 -> out [B][Nn][K] bf16 (transpose + convert)
__global__ void convert_w_kernel(const float* __restrict__ in, __hip_bfloat16* __restrict__ out,
                                 int K, int Nn) {
  __shared__ float tile[32][33];
  const float* src = in + (size_t)blockIdx.z * K * Nn;
  __hip_bfloat16* dst = out + (size_t)blockIdx.z * K * Nn;
  int n0 = blockIdx.x * 32, k0 = blockIdx.y * 32;
  int c = threadIdx.x & 31, r = threadIdx.x >> 5;
  #pragma unroll
  for (int i = 0; i < 4; i++)
    tile[r + i * 8][c] = src[(size_t)(k0 + r + i * 8) * Nn + n0 + c];
  __syncthreads();
  #pragma unroll
  for (int i = 0; i < 4; i++)
    dst[(size_t)(n0 + r + i * 8) * K + k0 + c] = __float2bfloat16(tile[c][r + i * 8]);
}

// ---------------- deterministic expert partition (LDS atomics only) ----------------
// 64 chunks x 256 assignments. hist -> scan -> scatter with block-local counters.

__global__ void hist_kernel(const int* __restrict__ top_e, int* __restrict__ chunkHist) {
  __shared__ int h[8];
  if (threadIdx.x < 8) h[threadIdx.x] = 0;
  __syncthreads();
  int a = blockIdx.x * 256 + threadIdx.x;
  atomicAdd(&h[top_e[a]], 1);
  __syncthreads();
  if (threadIdx.x < 8) chunkHist[blockIdx.x * 8 + threadIdx.x] = h[threadIdx.x];
}

__global__ void scan_kernel(const int* __restrict__ chunkHist, int* __restrict__ chunkBase,
                            int* __restrict__ counts, int* __restrict__ offs) {
  int e = threadIdx.x;
  if (e < 8) {
    int run = 0;
    for (int b = 0; b < 64; b++) { chunkBase[b * 8 + e] = run; run += chunkHist[b * 8 + e]; }
    counts[e] = run;
  }
  __syncthreads();
  if (e == 0) {
    int s = 0;
    for (int i = 0; i < 8; i++) { offs[i] = s; s += counts[i]; }
    offs[8] = s;
  }
  __syncthreads();
  if (e < 8) {
    int base = offs[e];
    for (int b = 0; b < 64; b++) chunkBase[b * 8 + e] += base;
  }
}

__global__ void scatter_kernel(const int* __restrict__ top_e, const float* __restrict__ top_w,
                               const int* __restrict__ chunkBase,
                               int* __restrict__ list, float* __restrict__ wlist) {
  __shared__ int lcnt[8];
  if (threadIdx.x < 8) lcnt[threadIdx.x] = 0;
  __syncthreads();
  int a = blockIdx.x * 256 + threadIdx.x;
  int e = top_e[a];
  int p = atomicAdd(&lcnt[e], 1);
  int pos = chunkBase[blockIdx.x * 8 + e] + p;
  list[pos] = a >> 1;
  wlist[pos] = top_w[a];
}

// ---------------- GEMM (m97-style 128x128 tile, BK=32) ----------------
// MODE 1: H = silu(X @ W1 + b1)   [shared blocks + routed gather blocks], K=1024, N=512
// MODE 2: out = Hs @ sW2 + sb2    [shared only, plain store],            K=512,  N=1024
// MODE 3: out += w * (Hr @ rW2 + rb2) [routed only, atomicAdd scatter],  K=512,  N=1024

template<int MODE>
__global__ __launch_bounds__(256, 2)
void gemm_kernel(const __hip_bfloat16* __restrict__ Abase,
                 const __hip_bfloat16* __restrict__ Ws,
                 const __hip_bfloat16* __restrict__ Wr,
                 const float* __restrict__ bs,
                 const float* __restrict__ br,
                 __hip_bfloat16* __restrict__ Hout,
                 float* __restrict__ Oout,
                 const int* __restrict__ counts,
                 const int* __restrict__ offs,
                 const int* __restrict__ list,
                 const float* __restrict__ wlist) {
  constexpr int K  = (MODE == 1) ? 1024 : 512;
  constexpr int NN = (MODE == 1) ? 512 : 1024;
  constexpr int LDB = K * 2;  // row bytes for both A and B (n-major weights)

  __shared__ __hip_bfloat16 Abuf[128 * 32];
  __shared__ __hip_bfloat16 Bbuf[128 * 32];
  __shared__ int tokens[128];

  int bid = blockIdx.x;
  int e = 0, mt, nt;
  bool rb = false;
  if (MODE == 1) {
    if (bid < 256) { mt = bid >> 2; nt = bid & 3; }
    else { rb = true; int q = bid - 256; e = q >> 8; q &= 255; mt = q >> 2; nt = q & 3; }
  } else if (MODE == 2) { mt = bid >> 3; nt = bid & 7; }
  else { rb = true; e = bid >> 9; int q = bid & 511; mt = q >> 3; nt = q & 7; }
  int m0 = mt * 128;
  int cnt = 128;
  if (rb) {
    int ce = counts[e];
    if (m0 >= ce) return;
    cnt = (ce - m0 < 128) ? (ce - m0) : 128;
  }

  const __hip_bfloat16* W = rb ? (Wr + (size_t)e * NN * K) : Ws;
  const float* bias = rb ? (br + e * NN) : bs;

  int tid = threadIdx.x, wid = tid >> 6, lane = tid & 63;
  if (MODE == 1) {
    if (tid < 128)
      tokens[tid] = rb ? ((tid < cnt) ? list[offs[e] + m0 + tid] : 0) : (m0 + tid);
    __syncthreads();
  }
  int arow0 = (MODE == 2) ? m0 : ((MODE == 3) ? (NTOK + offs[e] + m0) : 0);

  // staging source pointers (per-lane global addr; LDS written linearly by gload_lds)
  const char* aSrc[2];
  const char* bSrc[2];
  int ldsOff[2];
  #pragma unroll
  for (int c = 0; c < 2; c++) {
    int s = c * 4096 + wid * 1024 + lane * 16;
    int row = s >> 6;
    int chunk = (s >> 4) & 3;
    int sc = chunk ^ (row & 3);  // XOR-swizzle: pre-swizzled global source
    long ar = (MODE == 1) ? (long)tokens[row] : (long)(arow0 + row);
    aSrc[c] = (const char*)Abase + (size_t)ar * LDB + sc * 16;
    bSrc[c] = (const char*)W + (size_t)(nt * 128 + row) * LDB + sc * 16;
    ldsOff[c] = c * 4096 + wid * 1024;
  }

  int wm = wid >> 1, wn = wid & 1;
  int aoff[4], boff[4];
  #pragma unroll
  for (int m = 0; m < 4; m++) {
    int row = wm * 64 + m * 16 + (lane & 15);
    aoff[m] = row * 64 + (((lane >> 4) ^ (row & 3)) << 4);
  }
  #pragma unroll
  for (int n = 0; n < 4; n++) {
    int row = wn * 64 + n * 16 + (lane & 15);
    boff[n] = row * 64 + (((lane >> 4) ^ (row & 3)) << 4);
  }

  f32x4 zero = {0.f, 0.f, 0.f, 0.f};
  f32x4 acc[4][4];
  #pragma unroll
  for (int m = 0; m < 4; m++)
    #pragma unroll
    for (int n = 0; n < 4; n++) acc[m][n] = zero;

  char* ldsA = (char*)&Abuf[0];
  char* ldsB = (char*)&Bbuf[0];

  for (int kt = 0; kt < K / 32; ++kt) {
    __syncthreads();
    #pragma unroll
    for (int c = 0; c < 2; c++) gload16(aSrc[c] + (size_t)kt * 64, ldsA + ldsOff[c]);
    #pragma unroll
    for (int c = 0; c < 2; c++) gload16(bSrc[c] + (size_t)kt * 64, ldsB + ldsOff[c]);
    __syncthreads();
    bf16x8 a[4], b[4];
    #pragma unroll
    for (int m = 0; m < 4; m++) a[m] = *(const bf16x8*)(ldsA + aoff[m]);
    #pragma unroll
    for (int n = 0; n < 4; n++) b[n] = *(const bf16x8*)(ldsB + boff[n]);
    #pragma unroll
    for (int m = 0; m < 4; m++)
      #pragma unroll
      for (int n = 0; n < 4; n++)
        acc[m][n] = __builtin_amdgcn_mfma_f32_16x16x32_bf16(a[m], b[n], acc[m][n], 0, 0, 0);
  }

  int colBase = nt * 128 + wn * 64;
  if (MODE == 1) {
    size_t hrow0 = rb ? (size_t)(NTOK + offs[e] + m0) : (size_t)m0;
    #pragma unroll
    for (int m = 0; m < 4; m++) {
      #pragma unroll
      for (int r = 0; r < 4; r++) {
        int rl = wm * 64 + m * 16 + ((lane >> 4) << 2) + r;
        if (rl < cnt) {
          #pragma unroll
          for (int n = 0; n < 4; n++) {
            int col = colBase + n * 16 + (lane & 15);
            float v = acc[m][n][r] + bias[col];
            v = v / (1.f + __expf(-v));  // silu
            Hout[(hrow0 + rl) * HDIM + col] = __float2bfloat16(v);
          }
        }
      }
    }
  } else if (MODE == 2) {
    #pragma unroll
    for (int m = 0; m < 4; m++) {
      #pragma unroll
      for (int r = 0; r < 4; r++) {
        int rl = wm * 64 + m * 16 + ((lane >> 4) << 2) + r;
        size_t orow = (size_t)(m0 + rl);
        #pragma unroll
        for (int n = 0; n < 4; n++) {
          int col = colBase + n * 16 + (lane & 15);
          Oout[orow * DDIM + col] = acc[m][n][r] + bias[col];
        }
      }
    }
  } else {
    #pragma unroll
    for (int m = 0; m < 4; m++) {
      #pragma unroll
      for (int r = 0; r < 4; r++) {
        int rl = wm * 64 + m * 16 + ((lane >> 4) << 2) + r;
        if (rl < cnt) {
          int pos = offs[e] + m0 + rl;
          int tok = list[pos];
          float w = wlist[pos];
          #pragma unroll
          for (int n = 0; n < 4; n++) {
            int col = colBase + n * 16 + (lane & 15);
            atomicAdd(&Oout[(size_t)tok * DDIM + col], w * (acc[m][n][r] + bias[col]));
          }
        }
      }
    }
  }
}

// ---------------- launch ----------------

extern "C" void kernel_launch(void* const* d_in, const int* in_sizes, int n_in,
                              void* d_out, int out_size, void* d_ws, size_t ws_size,
                              hipStream_t stream) {
  const float* X   = (const float*)d_in[0];
  const float* rWt = (const float*)d_in[1];
  const float* eb  = (const float*)d_in[2];
  const float* sW1 = (const float*)d_in[3];
  const float* sb1 = (const float*)d_in[4];
  const float* sW2 = (const float*)d_in[5];
  const float* sb2 = (const float*)d_in[6];
  const float* rW1 = (const float*)d_in[7];
  const float* rb1 = (const float*)d_in[8];
  const float* rW2 = (const float*)d_in[9];
  const float* rb2 = (const float*)d_in[10];
  float* out = (float*)d_out;

  char* ws = (char*)d_ws;
  size_t off = 0;
  auto alloc = [&](size_t bytes) {
    char* p = ws + off;
    off += (bytes + 255) & ~(size_t)255;
    return p;
  };
  __hip_bfloat16* Xb   = (__hip_bfloat16*)alloc((size_t)NTOK * DDIM * 2);
  __hip_bfloat16* sW1t = (__hip_bfloat16*)alloc((size_t)HDIM * DDIM * 2);
  __hip_bfloat16* sW2t = (__hip_bfloat16*)alloc((size_t)DDIM * HDIM * 2);
  __hip_bfloat16* rW1t = (__hip_bfloat16*)alloc((size_t)8 * HDIM * DDIM * 2);
  __hip_bfloat16* rW2t = (__hip_bfloat16*)alloc((size_t)8 * DDIM * HDIM * 2);
  // Hbuf rows: [0,8192) shared H, [8192, 8192+16384) routed H (by assignment slot)
  __hip_bfloat16* Hbuf = (__hip_bfloat16*)alloc((size_t)(NTOK + 2 * NTOK) * HDIM * 2);
  alloc(131072);  // pad: MODE3 partial-tile A reads may run past Hbuf end
  int* counts    = (int*)alloc(64);
  int* offsA     = (int*)alloc(64);
  int* top_e     = (int*)alloc((size_t)NTOK * 2 * 4);
  float* top_w   = (float*)alloc((size_t)NTOK * 2 * 4);
  int* list      = (int*)alloc((size_t)NTOK * 2 * 4);
  float* wlist   = (float*)alloc((size_t)NTOK * 2 * 4);
  int* chunkHist = (int*)alloc(64 * 8 * 4);
  int* chunkBase = (int*)alloc(64 * 8 * 4);

  convert_route_kernel<<<2048, 256, 0, stream>>>(X, rWt, eb, Xb, top_e, top_w);
  convert_w_kernel<<<dim3(16, 32, 1), 256, 0, stream>>>(sW1, sW1t, 1024, 512);
  convert_w_kernel<<<dim3(32, 16, 1), 256, 0, stream>>>(sW2, sW2t, 512, 1024);
  convert_w_kernel<<<dim3(16, 32, 8), 256, 0, stream>>>(rW1, rW1t, 1024, 512);
  convert_w_kernel<<<dim3(32, 16, 8), 256, 0, stream>>>(rW2, rW2t, 512, 1024);
  hist_kernel<<<64, 256, 0, stream>>>(top_e, chunkHist);
  scan_kernel<<<1, 64, 0, stream>>>(chunkHist, chunkBase, counts, offsA);
  scatter_kernel<<<64, 256, 0, stream>>>(top_e, top_w, chunkBase, list, wlist);
  gemm_kernel<1><<<256 + 8 * 64 * 4, 256, 0, stream>>>(Xb, sW1t, rW1t, sb1, rb1, Hbuf, out,
                                                       counts, offsA, list, wlist);
  gemm_kernel<2><<<64 * 8, 256, 0, stream>>>(Hbuf, sW2t, rW2t, sb2, rb2, nullptr, out,
                                             counts, offsA, list, wlist);
  gemm_kernel<3><<<8 * 64 * 8, 256, 0, stream>>>(Hbuf, sW2t, rW2t, sb2, rb2, nullptr, out,
                                                 counts, offsA, list, wlist);
}

// Round 3
// 288.712 us; speedup vs baseline: 1.9474x; 1.1486x over previous
//
#include <hip/hip_runtime.h>
#include <hip/hip_bf16.h>
#include <stdint.h>

#define NTOK 8192
#define DDIM 1024
#define HDIM 512

typedef __attribute__((ext_vector_type(8))) __bf16 bf16x8;
typedef __attribute__((ext_vector_type(4))) float f32x4;
typedef __attribute__((ext_vector_type(4))) uint32_t u32x4;
typedef __attribute__((ext_vector_type(2))) uint32_t u32x2;

__device__ __forceinline__ void gload16(const void* g, void* lds) {
  __builtin_amdgcn_global_load_lds(
      (const __attribute__((address_space(1))) void*)g,
      (__attribute__((address_space(3))) void*)lds,
      16, 0, 0);
}

// ---------------- fused X convert + routing (NO global atomics) ----------------

__global__ __launch_bounds__(256)
void convert_route_kernel(const float* __restrict__ X, const float* __restrict__ rW,
                          const float* __restrict__ ebias,
                          __hip_bfloat16* __restrict__ Xb,
                          int* __restrict__ top_e, float* __restrict__ top_w) {
  int wid = threadIdx.x >> 6, lane = threadIdx.x & 63;
  int tok = blockIdx.x * 4 + wid;
  const float4* xr = (const float4*)(X + (size_t)tok * DDIM);
  u32x2* xb = (u32x2*)(Xb + (size_t)tok * DDIM);
  float acc[8];
  #pragma unroll
  for (int e = 0; e < 8; e++) acc[e] = 0.f;
  #pragma unroll
  for (int c = 0; c < 4; c++) {
    int j = c * 64 + lane;
    float4 x = xr[j];
    union { __hip_bfloat16 h[4]; u32x2 u; } cv;
    cv.h[0] = __float2bfloat16(x.x); cv.h[1] = __float2bfloat16(x.y);
    cv.h[2] = __float2bfloat16(x.z); cv.h[3] = __float2bfloat16(x.w);
    xb[j] = cv.u;
    #pragma unroll
    for (int e = 0; e < 8; e++) {
      float4 w = ((const float4*)(rW + (size_t)e * DDIM))[j];
      acc[e] += x.x * w.x + x.y * w.y + x.z * w.z + x.w * w.w;
    }
  }
  #pragma unroll
  for (int m = 1; m < 64; m <<= 1)
    #pragma unroll
    for (int e = 0; e < 8; e++) acc[e] += __shfl_xor(acc[e], m, 64);
  if (lane == 0) {
    float act[8];
    #pragma unroll
    for (int e = 0; e < 8; e++) {
      float x = acc[e] + ebias[e];
      float sp = (x > 15.f) ? x : log1pf(expf(x));
      act[e] = sqrtf(sp);
    }
    int e1 = 0; float v1 = act[0];
    #pragma unroll
    for (int e = 1; e < 8; e++) if (act[e] > v1) { v1 = act[e]; e1 = e; }
    int e2 = -1; float v2 = -1.f;
    #pragma unroll
    for (int e = 0; e < 8; e++) if (e != e1 && act[e] > v2) { v2 = act[e]; e2 = e; }
    top_e[tok * 2] = e1; top_e[tok * 2 + 1] = e2;
    top_w[tok * 2] = v1; top_w[tok * 2 + 1] = v2;
  }
}

// in [B][K][Nn] fp32 -> out [B][Nn][K] bf16 (transpose + convert)
__global__ void convert_w_kernel(const float* __restrict__ in, __hip_bfloat16* __restrict__ out,
                                 int K, int Nn) {
  __shared__ float tile[32][33];
  const float* src = in + (size_t)blockIdx.z * K * Nn;
  __hip_bfloat16* dst = out + (size_t)blockIdx.z * K * Nn;
  int n0 = blockIdx.x * 32, k0 = blockIdx.y * 32;
  int c = threadIdx.x & 31, r = threadIdx.x >> 5;
  #pragma unroll
  for (int i = 0; i < 4; i++)
    tile[r + i * 8][c] = src[(size_t)(k0 + r + i * 8) * Nn + n0 + c];
  __syncthreads();
  #pragma unroll
  for (int i = 0; i < 4; i++)
    dst[(size_t)(n0 + r + i * 8) * K + k0 + c] = __float2bfloat16(tile[c][r + i * 8]);
}

// ---------------- deterministic expert partition (LDS atomics only) ----------------

__global__ void hist_kernel(const int* __restrict__ top_e, int* __restrict__ chunkHist) {
  __shared__ int h[8];
  if (threadIdx.x < 8) h[threadIdx.x] = 0;
  __syncthreads();
  int a = blockIdx.x * 256 + threadIdx.x;
  atomicAdd(&h[top_e[a]], 1);
  __syncthreads();
  if (threadIdx.x < 8) chunkHist[blockIdx.x * 8 + threadIdx.x] = h[threadIdx.x];
}

__global__ void scan_kernel(const int* __restrict__ chunkHist, int* __restrict__ chunkBase,
                            int* __restrict__ counts, int* __restrict__ offs) {
  int e = threadIdx.x;
  if (e < 8) {
    int run = 0;
    for (int b = 0; b < 64; b++) { chunkBase[b * 8 + e] = run; run += chunkHist[b * 8 + e]; }
    counts[e] = run;
  }
  __syncthreads();
  if (e == 0) {
    int s = 0;
    for (int i = 0; i < 8; i++) { offs[i] = s; s += counts[i]; }
    offs[8] = s;
  }
  __syncthreads();
  if (e < 8) {
    int base = offs[e];
    for (int b = 0; b < 64; b++) chunkBase[b * 8 + e] += base;
  }
}

__global__ void scatter_kernel(const int* __restrict__ top_e, const float* __restrict__ top_w,
                               const int* __restrict__ chunkBase,
                               int* __restrict__ list, float* __restrict__ wlist,
                               int* __restrict__ inv) {
  __shared__ int lcnt[8];
  if (threadIdx.x < 8) lcnt[threadIdx.x] = 0;
  __syncthreads();
  int a = blockIdx.x * 256 + threadIdx.x;
  int e = top_e[a];
  int p = atomicAdd(&lcnt[e], 1);
  int pos = chunkBase[blockIdx.x * 8 + e] + p;
  list[pos] = a >> 1;
  wlist[pos] = top_w[a];
  inv[a] = pos;
}

// ---------------- final combine: out[tok] += y[slot0] + y[slot1] ----------------

__global__ __launch_bounds__(256)
void combine_kernel(const int* __restrict__ inv, const __hip_bfloat16* __restrict__ ybuf,
                    float* __restrict__ out) {
  int tok = blockIdx.x;
  int c = threadIdx.x * 4;
  int p0 = inv[tok * 2], p1 = inv[tok * 2 + 1];
  size_t o = (size_t)tok * DDIM + c;
  float4 v = *(const float4*)(out + o);
  union { u32x2 u; __hip_bfloat16 h[4]; } y0, y1;
  y0.u = *(const u32x2*)(ybuf + (size_t)p0 * DDIM + c);
  y1.u = *(const u32x2*)(ybuf + (size_t)p1 * DDIM + c);
  v.x += __bfloat162float(y0.h[0]) + __bfloat162float(y1.h[0]);
  v.y += __bfloat162float(y0.h[1]) + __bfloat162float(y1.h[1]);
  v.z += __bfloat162float(y0.h[2]) + __bfloat162float(y1.h[2]);
  v.w += __bfloat162float(y0.h[3]) + __bfloat162float(y1.h[3]);
  *(float4*)(out + o) = v;
}

// ---------------- GEMM (m97-style 128x128 tile, BK=32) ----------------
// MODE 1: H = silu(X @ W1 + b1)   [shared blocks + routed gather blocks], K=1024, N=512
// MODE 2: out = Hs @ sW2 + sb2    [shared only, plain store],            K=512,  N=1024
// MODE 3: ybuf[pos] = w*(Hr @ rW2 + rb2)  [routed, bf16 slot store],     K=512,  N=1024

template<int MODE>
__global__ __launch_bounds__(256, 2)
void gemm_kernel(const __hip_bfloat16* __restrict__ Abase,
                 const __hip_bfloat16* __restrict__ Ws,
                 const __hip_bfloat16* __restrict__ Wr,
                 const float* __restrict__ bs,
                 const float* __restrict__ br,
                 __hip_bfloat16* __restrict__ Hout,
                 float* __restrict__ Oout,
                 __hip_bfloat16* __restrict__ Ybuf,
                 const int* __restrict__ counts,
                 const int* __restrict__ offs,
                 const int* __restrict__ list,
                 const float* __restrict__ wlist) {
  constexpr int K  = (MODE == 1) ? 1024 : 512;
  constexpr int NN = (MODE == 1) ? 512 : 1024;
  constexpr int LDB = K * 2;  // row bytes for both A and B (n-major weights)

  __shared__ __hip_bfloat16 Abuf[128 * 32];
  __shared__ __hip_bfloat16 Bbuf[128 * 32];
  __shared__ int tokens[128];

  int bid = blockIdx.x;
  int e = 0, mt, nt;
  bool rb = false;
  if (MODE == 1) {
    if (bid < 256) { mt = bid >> 2; nt = bid & 3; }
    else { rb = true; int q = bid - 256; e = q >> 8; q &= 255; mt = q >> 2; nt = q & 3; }
  } else if (MODE == 2) { mt = bid >> 3; nt = bid & 7; }
  else { rb = true; e = bid >> 9; int q = bid & 511; mt = q >> 3; nt = q & 7; }
  int m0 = mt * 128;
  int cnt = 128;
  if (rb) {
    int ce = counts[e];
    if (m0 >= ce) return;
    cnt = (ce - m0 < 128) ? (ce - m0) : 128;
  }

  const __hip_bfloat16* W = rb ? (Wr + (size_t)e * NN * K) : Ws;
  const float* bias = rb ? (br + e * NN) : bs;

  int tid = threadIdx.x, wid = tid >> 6, lane = tid & 63;
  if (MODE == 1) {
    if (tid < 128)
      tokens[tid] = rb ? ((tid < cnt) ? list[offs[e] + m0 + tid] : 0) : (m0 + tid);
    __syncthreads();
  }
  int arow0 = (MODE == 2) ? m0 : ((MODE == 3) ? (NTOK + offs[e] + m0) : 0);

  const char* aSrc[2];
  const char* bSrc[2];
  int ldsOff[2];
  #pragma unroll
  for (int c = 0; c < 2; c++) {
    int s = c * 4096 + wid * 1024 + lane * 16;
    int row = s >> 6;
    int chunk = (s >> 4) & 3;
    int sc = chunk ^ (row & 3);  // XOR-swizzle: pre-swizzled global source
    long ar = (MODE == 1) ? (long)tokens[row] : (long)(arow0 + row);
    aSrc[c] = (const char*)Abase + (size_t)ar * LDB + sc * 16;
    bSrc[c] = (const char*)W + (size_t)(nt * 128 + row) * LDB + sc * 16;
    ldsOff[c] = c * 4096 + wid * 1024;
  }

  int wm = wid >> 1, wn = wid & 1;
  int aoff[4], boff[4];
  #pragma unroll
  for (int m = 0; m < 4; m++) {
    int row = wm * 64 + m * 16 + (lane & 15);
    aoff[m] = row * 64 + (((lane >> 4) ^ (row & 3)) << 4);
  }
  #pragma unroll
  for (int n = 0; n < 4; n++) {
    int row = wn * 64 + n * 16 + (lane & 15);
    boff[n] = row * 64 + (((lane >> 4) ^ (row & 3)) << 4);
  }

  f32x4 zero = {0.f, 0.f, 0.f, 0.f};
  f32x4 acc[4][4];
  #pragma unroll
  for (int m = 0; m < 4; m++)
    #pragma unroll
    for (int n = 0; n < 4; n++) acc[m][n] = zero;

  char* ldsA = (char*)&Abuf[0];
  char* ldsB = (char*)&Bbuf[0];

  for (int kt = 0; kt < K / 32; ++kt) {
    __syncthreads();
    #pragma unroll
    for (int c = 0; c < 2; c++) gload16(aSrc[c] + (size_t)kt * 64, ldsA + ldsOff[c]);
    #pragma unroll
    for (int c = 0; c < 2; c++) gload16(bSrc[c] + (size_t)kt * 64, ldsB + ldsOff[c]);
    __syncthreads();
    bf16x8 a[4], b[4];
    #pragma unroll
    for (int m = 0; m < 4; m++) a[m] = *(const bf16x8*)(ldsA + aoff[m]);
    #pragma unroll
    for (int n = 0; n < 4; n++) b[n] = *(const bf16x8*)(ldsB + boff[n]);
    #pragma unroll
    for (int m = 0; m < 4; m++)
      #pragma unroll
      for (int n = 0; n < 4; n++)
        acc[m][n] = __builtin_amdgcn_mfma_f32_16x16x32_bf16(a[m], b[n], acc[m][n], 0, 0, 0);
  }

  int colBase = nt * 128 + wn * 64;
  if (MODE == 1) {
    size_t hrow0 = rb ? (size_t)(NTOK + offs[e] + m0) : (size_t)m0;
    #pragma unroll
    for (int m = 0; m < 4; m++) {
      #pragma unroll
      for (int r = 0; r < 4; r++) {
        int rl = wm * 64 + m * 16 + ((lane >> 4) << 2) + r;
        if (rl < cnt) {
          #pragma unroll
          for (int n = 0; n < 4; n++) {
            int col = colBase + n * 16 + (lane & 15);
            float v = acc[m][n][r] + bias[col];
            v = v / (1.f + __expf(-v));  // silu
            Hout[(hrow0 + rl) * HDIM + col] = __float2bfloat16(v);
          }
        }
      }
    }
  } else if (MODE == 2) {
    #pragma unroll
    for (int m = 0; m < 4; m++) {
      #pragma unroll
      for (int r = 0; r < 4; r++) {
        int rl = wm * 64 + m * 16 + ((lane >> 4) << 2) + r;
        size_t orow = (size_t)(m0 + rl);
        #pragma unroll
        for (int n = 0; n < 4; n++) {
          int col = colBase + n * 16 + (lane & 15);
          Oout[orow * DDIM + col] = acc[m][n][r] + bias[col];
        }
      }
    }
  } else {
    #pragma unroll
    for (int m = 0; m < 4; m++) {
      #pragma unroll
      for (int r = 0; r < 4; r++) {
        int rl = wm * 64 + m * 16 + ((lane >> 4) << 2) + r;
        if (rl < cnt) {
          int pos = offs[e] + m0 + rl;
          float w = wlist[pos];
          #pragma unroll
          for (int n = 0; n < 4; n++) {
            int col = colBase + n * 16 + (lane & 15);
            Ybuf[(size_t)pos * DDIM + col] = __float2bfloat16(w * (acc[m][n][r] + bias[col]));
          }
        }
      }
    }
  }
}

// ---------------- launch ----------------

extern "C" void kernel_launch(void* const* d_in, const int* in_sizes, int n_in,
                              void* d_out, int out_size, void* d_ws, size_t ws_size,
                              hipStream_t stream) {
  const float* X   = (const float*)d_in[0];
  const float* rWt = (const float*)d_in[1];
  const float* eb  = (const float*)d_in[2];
  const float* sW1 = (const float*)d_in[3];
  const float* sb1 = (const float*)d_in[4];
  const float* sW2 = (const float*)d_in[5];
  const float* sb2 = (const float*)d_in[6];
  const float* rW1 = (const float*)d_in[7];
  const float* rb1 = (const float*)d_in[8];
  const float* rW2 = (const float*)d_in[9];
  const float* rb2 = (const float*)d_in[10];
  float* out = (float*)d_out;

  char* ws = (char*)d_ws;
  size_t off = 0;
  auto alloc = [&](size_t bytes) {
    char* p = ws + off;
    off += (bytes + 255) & ~(size_t)255;
    return p;
  };
  // Region 0 (32 MB): {Xb 16MB, sW1t 1MB, rW1t 8MB} during phase 1; aliased by
  // Ybuf (16384 slots x 1024 bf16 = 32 MB) during phase 2 (time-disjoint: all
  // phase-1 tenants are dead once gemm<1> completes; Ybuf written by gemm<3>).
  char* region0 = alloc((size_t)16384 * DDIM * 2);
  __hip_bfloat16* Xb   = (__hip_bfloat16*)region0;
  __hip_bfloat16* sW1t = (__hip_bfloat16*)(region0 + (size_t)NTOK * DDIM * 2);
  __hip_bfloat16* rW1t = (__hip_bfloat16*)(region0 + (size_t)NTOK * DDIM * 2
                                                   + (size_t)HDIM * DDIM * 2);
  __hip_bfloat16* Ybuf = (__hip_bfloat16*)region0;

  __hip_bfloat16* sW2t = (__hip_bfloat16*)alloc((size_t)DDIM * HDIM * 2);
  __hip_bfloat16* rW2t = (__hip_bfloat16*)alloc((size_t)8 * DDIM * HDIM * 2);
  // Hbuf rows: [0,8192) shared H, [8192, 8192+16384) routed H (by assignment slot)
  __hip_bfloat16* Hbuf = (__hip_bfloat16*)alloc((size_t)(NTOK + 2 * NTOK) * HDIM * 2);
  alloc(131072);  // pad: MODE3 partial-tile A reads may run past Hbuf end
  int* counts    = (int*)alloc(64);
  int* offsA     = (int*)alloc(64);
  int* top_e     = (int*)alloc((size_t)NTOK * 2 * 4);
  float* top_w   = (float*)alloc((size_t)NTOK * 2 * 4);
  int* list      = (int*)alloc((size_t)NTOK * 2 * 4);
  float* wlist   = (float*)alloc((size_t)NTOK * 2 * 4);
  int* inv       = (int*)alloc((size_t)NTOK * 2 * 4);
  int* chunkHist = (int*)alloc(64 * 8 * 4);
  int* chunkBase = (int*)alloc(64 * 8 * 4);

  convert_route_kernel<<<2048, 256, 0, stream>>>(X, rWt, eb, Xb, top_e, top_w);
  convert_w_kernel<<<dim3(16, 32, 1), 256, 0, stream>>>(sW1, sW1t, 1024, 512);
  convert_w_kernel<<<dim3(32, 16, 1), 256, 0, stream>>>(sW2, sW2t, 512, 1024);
  convert_w_kernel<<<dim3(16, 32, 8), 256, 0, stream>>>(rW1, rW1t, 1024, 512);
  convert_w_kernel<<<dim3(32, 16, 8), 256, 0, stream>>>(rW2, rW2t, 512, 1024);
  hist_kernel<<<64, 256, 0, stream>>>(top_e, chunkHist);
  scan_kernel<<<1, 64, 0, stream>>>(chunkHist, chunkBase, counts, offsA);
  scatter_kernel<<<64, 256, 0, stream>>>(top_e, top_w, chunkBase, list, wlist, inv);
  gemm_kernel<1><<<256 + 8 * 64 * 4, 256, 0, stream>>>(Xb, sW1t, rW1t, sb1, rb1, Hbuf, out,
                                                       nullptr, counts, offsA, list, wlist);
  gemm_kernel<2><<<64 * 8, 256, 0, stream>>>(Hbuf, sW2t, rW2t, sb2, rb2, nullptr, out,
                                             nullptr, counts, offsA, list, wlist);
  gemm_kernel<3><<<8 * 64 * 8, 256, 0, stream>>>(Hbuf, sW2t, rW2t, sb2, rb2, nullptr, out,
                                                 Ybuf, counts, offsA, list, wlist);
  combine_kernel<<<NTOK, 256, 0, stream>>>(inv, Ybuf, out);
}

// Round 4
// 264.115 us; speedup vs baseline: 2.1287x; 1.0931x over previous
//
#include <hip/hip_runtime.h>
#include <hip/hip_bf16.h>
#include <stdint.h>

#define NTOK 8192
#define DDIM 1024
#define HDIM 512

typedef __attribute__((ext_vector_type(8))) __bf16 bf16x8;
typedef __attribute__((ext_vector_type(4))) float f32x4;
typedef __attribute__((ext_vector_type(4))) uint32_t u32x4;
typedef __attribute__((ext_vector_type(2))) uint32_t u32x2;

__device__ __forceinline__ void gload16(const void* g, void* lds) {
  __builtin_amdgcn_global_load_lds(
      (const __attribute__((address_space(1))) void*)g,
      (__attribute__((address_space(3))) void*)lds,
      16, 0, 0);
}

// ---------------- fused X convert + routing (NO global atomics) ----------------

__global__ __launch_bounds__(256)
void convert_route_kernel(const float* __restrict__ X, const float* __restrict__ rW,
                          const float* __restrict__ ebias,
                          __hip_bfloat16* __restrict__ Xb,
                          int* __restrict__ top_e, float* __restrict__ top_w) {
  int wid = threadIdx.x >> 6, lane = threadIdx.x & 63;
  int tok = blockIdx.x * 4 + wid;
  const float4* xr = (const float4*)(X + (size_t)tok * DDIM);
  u32x2* xb = (u32x2*)(Xb + (size_t)tok * DDIM);
  float acc[8];
  #pragma unroll
  for (int e = 0; e < 8; e++) acc[e] = 0.f;
  #pragma unroll
  for (int c = 0; c < 4; c++) {
    int j = c * 64 + lane;
    float4 x = xr[j];
    union { __hip_bfloat16 h[4]; u32x2 u; } cv;
    cv.h[0] = __float2bfloat16(x.x); cv.h[1] = __float2bfloat16(x.y);
    cv.h[2] = __float2bfloat16(x.z); cv.h[3] = __float2bfloat16(x.w);
    xb[j] = cv.u;
    #pragma unroll
    for (int e = 0; e < 8; e++) {
      float4 w = ((const float4*)(rW + (size_t)e * DDIM))[j];
      acc[e] += x.x * w.x + x.y * w.y + x.z * w.z + x.w * w.w;
    }
  }
  #pragma unroll
  for (int m = 1; m < 64; m <<= 1)
    #pragma unroll
    for (int e = 0; e < 8; e++) acc[e] += __shfl_xor(acc[e], m, 64);
  if (lane == 0) {
    float act[8];
    #pragma unroll
    for (int e = 0; e < 8; e++) {
      float x = acc[e] + ebias[e];
      float sp = (x > 15.f) ? x : log1pf(expf(x));
      act[e] = sqrtf(sp);
    }
    int e1 = 0; float v1 = act[0];
    #pragma unroll
    for (int e = 1; e < 8; e++) if (act[e] > v1) { v1 = act[e]; e1 = e; }
    int e2 = -1; float v2 = -1.f;
    #pragma unroll
    for (int e = 0; e < 8; e++) if (e != e1 && act[e] > v2) { v2 = act[e]; e2 = e; }
    top_e[tok * 2] = e1; top_e[tok * 2 + 1] = e2;
    top_w[tok * 2] = v1; top_w[tok * 2 + 1] = v2;
  }
}

// fused W1-family / W2-family transpose+convert: z=0 -> shared, z>=1 -> expert z-1
__global__ void convert_w_kernel(const float* __restrict__ sIn, const float* __restrict__ rIn,
                                 __hip_bfloat16* __restrict__ sOut, __hip_bfloat16* __restrict__ rOut,
                                 int K, int Nn) {
  __shared__ float tile[32][33];
  int z = blockIdx.z;
  const float* src = (z == 0) ? sIn : rIn + (size_t)(z - 1) * K * Nn;
  __hip_bfloat16* dst = (z == 0) ? sOut : rOut + (size_t)(z - 1) * K * Nn;
  int n0 = blockIdx.x * 32, k0 = blockIdx.y * 32;
  int c = threadIdx.x & 31, r = threadIdx.x >> 5;
  #pragma unroll
  for (int i = 0; i < 4; i++)
    tile[r + i * 8][c] = src[(size_t)(k0 + r + i * 8) * Nn + n0 + c];
  __syncthreads();
  #pragma unroll
  for (int i = 0; i < 4; i++)
    dst[(size_t)(n0 + r + i * 8) * K + k0 + c] = __float2bfloat16(tile[c][r + i * 8]);
}

// ---------------- deterministic expert partition (LDS atomics only) ----------------

__global__ void hist_kernel(const int* __restrict__ top_e, int* __restrict__ chunkHist) {
  __shared__ int h[8];
  if (threadIdx.x < 8) h[threadIdx.x] = 0;
  __syncthreads();
  int a = blockIdx.x * 256 + threadIdx.x;
  atomicAdd(&h[top_e[a]], 1);
  __syncthreads();
  if (threadIdx.x < 8) chunkHist[blockIdx.x * 8 + threadIdx.x] = h[threadIdx.x];
}

__global__ void scan_kernel(const int* __restrict__ chunkHist, int* __restrict__ chunkBase,
                            int* __restrict__ counts, int* __restrict__ offs,
                            int* __restrict__ tiles) {
  int e = threadIdx.x;
  if (e < 8) {
    int run = 0;
    for (int b = 0; b < 64; b++) { chunkBase[b * 8 + e] = run; run += chunkHist[b * 8 + e]; }
    counts[e] = run;
  }
  __syncthreads();
  if (e == 0) {
    int s = 0;
    for (int i = 0; i < 8; i++) { offs[i] = s; s += counts[i]; }
    offs[8] = s;
    int tb = 0;
    for (int i = 0; i < 8; i++) { tiles[i] = tb; tb += (counts[i] + 127) >> 7; }
    tiles[8] = tb;  // total routed 128-row tiles (<=135)
  }
  __syncthreads();
  if (e < 8) {
    int base = offs[e];
    for (int b = 0; b < 64; b++) chunkBase[b * 8 + e] += base;
  }
}

__global__ void scatter_kernel(const int* __restrict__ top_e, const float* __restrict__ top_w,
                               const int* __restrict__ chunkBase,
                               int* __restrict__ list, float* __restrict__ wlist,
                               int* __restrict__ inv) {
  __shared__ int lcnt[8];
  if (threadIdx.x < 8) lcnt[threadIdx.x] = 0;
  __syncthreads();
  int a = blockIdx.x * 256 + threadIdx.x;
  int e = top_e[a];
  int p = atomicAdd(&lcnt[e], 1);
  int pos = chunkBase[blockIdx.x * 8 + e] + p;
  list[pos] = a >> 1;
  wlist[pos] = top_w[a];
  inv[a] = pos;
}

// ---------------- final combine: out[tok] += y[slot0] + y[slot1] ----------------

__global__ __launch_bounds__(256)
void combine_kernel(const int* __restrict__ inv, const __hip_bfloat16* __restrict__ ybuf,
                    float* __restrict__ out) {
  int tok = blockIdx.x;
  int c = threadIdx.x * 4;
  int p0 = inv[tok * 2], p1 = inv[tok * 2 + 1];
  size_t o = (size_t)tok * DDIM + c;
  float4 v = *(const float4*)(out + o);
  union { u32x2 u; __hip_bfloat16 h[4]; } y0, y1;
  y0.u = *(const u32x2*)(ybuf + (size_t)p0 * DDIM + c);
  y1.u = *(const u32x2*)(ybuf + (size_t)p1 * DDIM + c);
  v.x += __bfloat162float(y0.h[0]) + __bfloat162float(y1.h[0]);
  v.y += __bfloat162float(y0.h[1]) + __bfloat162float(y1.h[1]);
  v.z += __bfloat162float(y0.h[2]) + __bfloat162float(y1.h[2]);
  v.w += __bfloat162float(y0.h[3]) + __bfloat162float(y1.h[3]);
  *(float4*)(out + o) = v;
}

// ---------------- GEMM (128x128 tile, BK=32, dense tile list + XCD swizzle) ----
// MODE 1 : H = silu(X@W1+b1); logical [0,256) shared tokens, [256,..) routed gather
// MODE 23: logical [0,512) -> out = Hs@sW2+sb2 (fp32 store)
//          logical [512,..) -> ybuf[pos] = w*(Hr@rW2+rb2) (bf16 store)

template<int MODE>
__global__ __launch_bounds__(256, 4)
void gemm_kernel(const __hip_bfloat16* __restrict__ Abase,
                 const __hip_bfloat16* __restrict__ Ws,
                 const __hip_bfloat16* __restrict__ Wr,
                 const float* __restrict__ bs,
                 const float* __restrict__ br,
                 __hip_bfloat16* __restrict__ Hout,
                 float* __restrict__ Oout,
                 __hip_bfloat16* __restrict__ Ybuf,
                 const int* __restrict__ counts,
                 const int* __restrict__ offs,
                 const int* __restrict__ tiles,
                 const int* __restrict__ list,
                 const float* __restrict__ wlist) {
  constexpr int K   = (MODE == 1) ? 1024 : 512;
  constexpr int NN  = (MODE == 1) ? 512 : 1024;
  constexpr int LDB = K * 2;
  constexpr int SH  = (MODE == 1) ? 256 : 512;  // # shared logical blocks
  constexpr int LNT = (MODE == 1) ? 2 : 3;      // log2(n-tiles)

  __shared__ __hip_bfloat16 Abuf[128 * 32];
  __shared__ __hip_bfloat16 Bbuf[128 * 32];
  __shared__ int tokens[128];

  // bijective XCD-chunked swizzle (grid % 8 == 0): same-A-tile blocks contiguous
  int l = ((blockIdx.x & 7) * (gridDim.x >> 3)) + (blockIdx.x >> 3);

  int e = 0, mt, nt;
  bool rb = false;
  if (l < SH) { mt = l >> LNT; nt = l & ((1 << LNT) - 1); }
  else {
    rb = true;
    int rq = l - SH;
    int rt = rq >> LNT; nt = rq & ((1 << LNT) - 1);
    if (rt >= tiles[8]) return;
    while (e < 7 && rt >= tiles[e + 1]) ++e;
    mt = rt - tiles[e];
  }
  int m0 = mt * 128;
  int cnt = 128;
  if (rb) {
    int ce = counts[e];
    cnt = (ce - m0 < 128) ? (ce - m0) : 128;
  }

  const __hip_bfloat16* W = rb ? (Wr + (size_t)e * NN * K) : Ws;
  const float* bias = rb ? (br + e * NN) : bs;

  int tid = threadIdx.x, wid = tid >> 6, lane = tid & 63;
  if (MODE == 1) {
    if (tid < 128)
      tokens[tid] = rb ? ((tid < cnt) ? list[offs[e] + m0 + tid] : 0) : (m0 + tid);
    __syncthreads();
  }
  int arow0 = rb ? (NTOK + offs[e] + m0) : m0;  // MODE 23 only

  const char* aSrc[2];
  const char* bSrc[2];
  int ldsOff[2];
  #pragma unroll
  for (int c = 0; c < 2; c++) {
    int s = c * 4096 + wid * 1024 + lane * 16;
    int row = s >> 6;
    int chunk = (s >> 4) & 3;
    int sc = chunk ^ (row & 3);  // XOR-swizzle via pre-swizzled global source
    long ar = (MODE == 1) ? (long)tokens[row] : (long)(arow0 + row);
    aSrc[c] = (const char*)Abase + (size_t)ar * LDB + sc * 16;
    bSrc[c] = (const char*)W + (size_t)(nt * 128 + row) * LDB + sc * 16;
    ldsOff[c] = c * 4096 + wid * 1024;
  }

  int wm = wid >> 1, wn = wid & 1;
  int aoff[4], boff[4];
  #pragma unroll
  for (int m = 0; m < 4; m++) {
    int row = wm * 64 + m * 16 + (lane & 15);
    aoff[m] = row * 64 + (((lane >> 4) ^ (row & 3)) << 4);
  }
  #pragma unroll
  for (int n = 0; n < 4; n++) {
    int row = wn * 64 + n * 16 + (lane & 15);
    boff[n] = row * 64 + (((lane >> 4) ^ (row & 3)) << 4);
  }

  f32x4 zero = {0.f, 0.f, 0.f, 0.f};
  f32x4 acc[4][4];
  #pragma unroll
  for (int m = 0; m < 4; m++)
    #pragma unroll
    for (int n = 0; n < 4; n++) acc[m][n] = zero;

  char* ldsA = (char*)&Abuf[0];
  char* ldsB = (char*)&Bbuf[0];

  for (int kt = 0; kt < K / 32; ++kt) {
    __syncthreads();
    #pragma unroll
    for (int c = 0; c < 2; c++) gload16(aSrc[c] + (size_t)kt * 64, ldsA + ldsOff[c]);
    #pragma unroll
    for (int c = 0; c < 2; c++) gload16(bSrc[c] + (size_t)kt * 64, ldsB + ldsOff[c]);
    __syncthreads();
    bf16x8 a[4], b[4];
    #pragma unroll
    for (int m = 0; m < 4; m++) a[m] = *(const bf16x8*)(ldsA + aoff[m]);
    #pragma unroll
    for (int n = 0; n < 4; n++) b[n] = *(const bf16x8*)(ldsB + boff[n]);
    #pragma unroll
    for (int m = 0; m < 4; m++)
      #pragma unroll
      for (int n = 0; n < 4; n++)
        acc[m][n] = __builtin_amdgcn_mfma_f32_16x16x32_bf16(a[m], b[n], acc[m][n], 0, 0, 0);
  }

  int colBase = nt * 128 + wn * 64;
  if (MODE == 1) {
    size_t hrow0 = rb ? (size_t)(NTOK + offs[e] + m0) : (size_t)m0;
    #pragma unroll
    for (int m = 0; m < 4; m++) {
      #pragma unroll
      for (int r = 0; r < 4; r++) {
        int rl = wm * 64 + m * 16 + ((lane >> 4) << 2) + r;
        if (rl < cnt) {
          #pragma unroll
          for (int n = 0; n < 4; n++) {
            int col = colBase + n * 16 + (lane & 15);
            float v = acc[m][n][r] + bias[col];
            v = v / (1.f + __expf(-v));  // silu
            Hout[(hrow0 + rl) * HDIM + col] = __float2bfloat16(v);
          }
        }
      }
    }
  } else if (!rb) {
    #pragma unroll
    for (int m = 0; m < 4; m++) {
      #pragma unroll
      for (int r = 0; r < 4; r++) {
        int rl = wm * 64 + m * 16 + ((lane >> 4) << 2) + r;
        size_t orow = (size_t)(m0 + rl);
        #pragma unroll
        for (int n = 0; n < 4; n++) {
          int col = colBase + n * 16 + (lane & 15);
          Oout[orow * DDIM + col] = acc[m][n][r] + bias[col];
        }
      }
    }
  } else {
    #pragma unroll
    for (int m = 0; m < 4; m++) {
      #pragma unroll
      for (int r = 0; r < 4; r++) {
        int rl = wm * 64 + m * 16 + ((lane >> 4) << 2) + r;
        if (rl < cnt) {
          int pos = offs[e] + m0 + rl;
          float w = wlist[pos];
          #pragma unroll
          for (int n = 0; n < 4; n++) {
            int col = colBase + n * 16 + (lane & 15);
            Ybuf[(size_t)pos * DDIM + col] = __float2bfloat16(w * (acc[m][n][r] + bias[col]));
          }
        }
      }
    }
  }
}

// ---------------- launch ----------------

extern "C" void kernel_launch(void* const* d_in, const int* in_sizes, int n_in,
                              void* d_out, int out_size, void* d_ws, size_t ws_size,
                              hipStream_t stream) {
  const float* X   = (const float*)d_in[0];
  const float* rWt = (const float*)d_in[1];
  const float* eb  = (const float*)d_in[2];
  const float* sW1 = (const float*)d_in[3];
  const float* sb1 = (const float*)d_in[4];
  const float* sW2 = (const float*)d_in[5];
  const float* sb2 = (const float*)d_in[6];
  const float* rW1 = (const float*)d_in[7];
  const float* rb1 = (const float*)d_in[8];
  const float* rW2 = (const float*)d_in[9];
  const float* rb2 = (const float*)d_in[10];
  float* out = (float*)d_out;

  char* ws = (char*)d_ws;
  size_t off = 0;
  auto alloc = [&](size_t bytes) {
    char* p = ws + off;
    off += (bytes + 255) & ~(size_t)255;
    return p;
  };
  // Region 0 (32 MB): {Xb, sW1t, rW1t} live through gemm<1>; aliased afterward
  // by Ybuf (16384 x 1024 bf16), written by gemm<23> routed blocks.
  char* region0 = alloc((size_t)16384 * DDIM * 2);
  __hip_bfloat16* Xb   = (__hip_bfloat16*)region0;
  __hip_bfloat16* sW1t = (__hip_bfloat16*)(region0 + (size_t)NTOK * DDIM * 2);
  __hip_bfloat16* rW1t = (__hip_bfloat16*)(region0 + (size_t)NTOK * DDIM * 2
                                                   + (size_t)HDIM * DDIM * 2);
  __hip_bfloat16* Ybuf = (__hip_bfloat16*)region0;

  __hip_bfloat16* sW2t = (__hip_bfloat16*)alloc((size_t)DDIM * HDIM * 2);
  __hip_bfloat16* rW2t = (__hip_bfloat16*)alloc((size_t)8 * DDIM * HDIM * 2);
  __hip_bfloat16* Hbuf = (__hip_bfloat16*)alloc((size_t)(NTOK + 2 * NTOK) * HDIM * 2);
  alloc(131072);  // pad: partial-tile A reads may run past Hbuf end
  int* counts    = (int*)alloc(64);
  int* offsA     = (int*)alloc(64);
  int* tiles     = (int*)alloc(64);
  int* top_e     = (int*)alloc((size_t)NTOK * 2 * 4);
  float* top_w   = (float*)alloc((size_t)NTOK * 2 * 4);
  int* list      = (int*)alloc((size_t)NTOK * 2 * 4);
  float* wlist   = (float*)alloc((size_t)NTOK * 2 * 4);
  int* inv       = (int*)alloc((size_t)NTOK * 2 * 4);
  int* chunkHist = (int*)alloc(64 * 8 * 4);
  int* chunkBase = (int*)alloc(64 * 8 * 4);

  convert_route_kernel<<<2048, 256, 0, stream>>>(X, rWt, eb, Xb, top_e, top_w);
  convert_w_kernel<<<dim3(16, 32, 9), 256, 0, stream>>>(sW1, rW1, sW1t, rW1t, 1024, 512);
  convert_w_kernel<<<dim3(32, 16, 9), 256, 0, stream>>>(sW2, rW2, sW2t, rW2t, 512, 1024);
  hist_kernel<<<64, 256, 0, stream>>>(top_e, chunkHist);
  scan_kernel<<<1, 64, 0, stream>>>(chunkHist, chunkBase, counts, offsA, tiles);
  scatter_kernel<<<64, 256, 0, stream>>>(top_e, top_w, chunkBase, list, wlist, inv);
  // grids: shared + 4or8 * 136 max routed tiles; both % 8 == 0 for the swizzle
  gemm_kernel<1><<<256 + 4 * 136, 256, 0, stream>>>(Xb, sW1t, rW1t, sb1, rb1, Hbuf, out,
                                                    nullptr, counts, offsA, tiles, list, wlist);
  gemm_kernel<23><<<512 + 8 * 136, 256, 0, stream>>>(Hbuf, sW2t, rW2t, sb2, rb2, nullptr, out,
                                                     Ybuf, counts, offsA, tiles, list, wlist);
  combine_kernel<<<NTOK, 256, 0, stream>>>(inv, Ybuf, out);
}